// Round 8
// baseline (261.870 us; speedup 1.0000x reference)
//
#include <hip/hip_runtime.h>

typedef unsigned short u16;
typedef unsigned int u32;
typedef __attribute__((ext_vector_type(8))) short short8;
typedef __attribute__((ext_vector_type(4))) float f32x4;

#define N_NODES 16384
#define B_MOL   256
#define NPM     64
#define E_EDGES 65536
#define FMAXF   32
#define AMAXA   16
#define HID     960
#define NFG     205
#define BF_ROWS 8192
#define OUT1    7864320   // B*FMAX*HID
#define NTOT    4516800   // total normalized elements

__device__ __forceinline__ float bf2f(u16 u){ u32 x=((u32)u)<<16; float f; __builtin_memcpy(&f,&x,4); return f; }
__device__ __forceinline__ u16 f2bf(float f){ u32 x; __builtin_memcpy(&x,&f,4); x += 0x7FFFu + ((x>>16)&1u); return (u16)(x>>16); }

__device__ __forceinline__ void gload_lds16(const u16* g, u16* l){
    __builtin_amdgcn_global_load_lds(
        (const __attribute__((address_space(1))) void*)g,
        (__attribute__((address_space(3))) void*)l, 16, 0, 0);
}
// swizzled fragment-region address (16-row x 32-col regions of a 960-col matrix)
__device__ __forceinline__ size_t swzA(int row, int col){      // col multiple of 8, u16 units
    return ((size_t)((row>>4)*30 + (col>>5)))*512 + (size_t)(((((col>>3)&3)*16) + (row&15))*8);
}
__device__ __forceinline__ size_t swzE(int row, int col){      // element-granular
    return ((size_t)((row>>4)*30 + (col>>5)))*512 + (size_t)((((col>>3)&3)*16 + (row&15))*8 + (col&7));
}

struct NormSrcs { const void* p[11]; };
// all 11 float tensors -> contiguous bf16 region; 8 elements per thread (all segment
// boundaries are multiples of 8). per-block dtype flag; b2f/projbf fp32; zero deg + bias-accum
__global__ __launch_bounds__(256) void k_normAll(NormSrcs s, u16* __restrict__ region,
                                                 float* __restrict__ b2f, float* __restrict__ projbf,
                                                 float* __restrict__ z4, int* __restrict__ flag,
                                                 int* __restrict__ deg){
    __shared__ int cnt;
    int t = threadIdx.x;
    if (t==0) cnt = 0;
    __syncthreads();
    u16 pv = ((const u16*)s.p[0])[t*2];
    if (((pv>>7)&0xFF) >= 0xC0) atomicAdd(&cnt, 1);
    __syncthreads();
    int fl = (cnt > 16) ? 1 : 0;              // 1 => inputs are fp32
    int gid = blockIdx.x*256 + t;
    if (blockIdx.x==0 && t==0) *flag = fl;
    int base = gid*8;
    const f32x4 zf = {0.f,0.f,0.f,0.f};
    if (base < N_NODES){ *(f32x4*)(deg+base) = zf; *(f32x4*)(deg+base+4) = zf; }
    if (base < 4*HID)  { *(f32x4*)(z4+base)  = zf; *(f32x4*)(z4+base+4)  = zf; }
    if (base >= NTOT) return;
    int seg, off;
    if      (base <   81920){seg=0;  off=base;}
    else if (base <   86720){seg=1;  off=base-81920;}
    else if (base <   87680){seg=2;  off=base-86720;}
    else if (base < 1009280){seg=3;  off=base-87680;}
    else if (base < 1010240){seg=4;  off=base-1009280;}
    else if (base < 1115200){seg=5;  off=base-1010240;}
    else if (base < 1135680){seg=6;  off=base-1115200;}
    else if (base < 2057280){seg=7;  off=base-1135680;}
    else if (base < 2058240){seg=8;  off=base-2057280;}
    else if (base < 4515840){seg=9;  off=base-2058240;}
    else                    {seg=10; off=base-4515840;}
    const void* sp = s.p[seg];
    short8 ov;
    float fvs[8];
    if (fl){
        const float* fp = (const float*)sp + off;
        f32x4 v0 = *(const f32x4*)(fp);
        f32x4 v1 = *(const f32x4*)(fp+4);
        #pragma unroll
        for (int j=0;j<4;j++){ fvs[j]=v0[j]; fvs[4+j]=v1[j]; }
        #pragma unroll
        for (int j=0;j<8;j++) ((u16*)&ov)[j] = f2bf(fvs[j]);
    } else {
        ov = *(const short8*)((const u16*)sp + off);
        #pragma unroll
        for (int j=0;j<8;j++) fvs[j] = bf2f(((u16*)&ov)[j]);
    }
    *(short8*)(region + base) = ov;
    if (seg==4){
        *(f32x4*)(b2f+off)   = (f32x4){fvs[0],fvs[1],fvs[2],fvs[3]};
        *(f32x4*)(b2f+off+4) = (f32x4){fvs[4],fvs[5],fvs[6],fvs[7]};
    }
    if (seg==8){
        *(f32x4*)(projbf+off)   = (f32x4){fvs[0],fvs[1],fvs[2],fvs[3]};
        *(f32x4*)(projbf+off+4) = (f32x4){fvs[4],fvs[5],fvs[6],fvs[7]};
    }
}

// ================= device bodies (parameterized by block coords + smem) =================

// square-960 bf16 GEMM: C = A @ Bt^T (bf16 out; optional swizzled store)
// register-staged prefetch: next k-chunk issued right after the top barrier.
__device__ __forceinline__ void gemm_sq(int bx, int by, const u16* __restrict__ A, int lda,
                                        const u16* __restrict__ Bt, int ldb,
                                        u16* __restrict__ C, int swz, char* smem)
{
    u16* As = (u16*)smem;            // 64*40
    u16* Bs = (u16*)smem + 64*40;
    const int tid = threadIdx.x;
    const int wave = tid>>6, lane = tid&63;
    const int wm = wave>>1, wn = wave&1;
    const int q = lane>>4, l16 = lane&15;
    const int m0 = bx*64, n0 = by*64;
    const int sm = tid>>2, sk = (tid&3)*8;
    f32x4 acc00={0,0,0,0}, acc01={0,0,0,0}, acc10={0,0,0,0}, acc11={0,0,0,0};
    const u16* Ap = A + (size_t)(m0+sm)*lda + sk;
    const u16* Bp = Bt + (size_t)(n0+sm)*ldb + sk;
    short8 av = *(const short8*)(Ap);
    short8 bv = *(const short8*)(Bp);
    for (int k0=0; k0<HID; k0+=32){
        *(short8*)(As + sm*40 + sk) = av;
        *(short8*)(Bs + sm*40 + sk) = bv;
        __syncthreads();
        if (k0+32 < HID){
            av = *(const short8*)(Ap + k0 + 32);
            bv = *(const short8*)(Bp + k0 + 32);
        }
        short8 a0 = *(const short8*)(As + (wm*32      + l16)*40 + q*8);
        short8 a1 = *(const short8*)(As + (wm*32 + 16 + l16)*40 + q*8);
        short8 b0 = *(const short8*)(Bs + (wn*32      + l16)*40 + q*8);
        short8 b1 = *(const short8*)(Bs + (wn*32 + 16 + l16)*40 + q*8);
        acc00 = __builtin_amdgcn_mfma_f32_16x16x32_bf16(a0,b0,acc00,0,0,0);
        acc01 = __builtin_amdgcn_mfma_f32_16x16x32_bf16(a0,b1,acc01,0,0,0);
        acc10 = __builtin_amdgcn_mfma_f32_16x16x32_bf16(a1,b0,acc10,0,0,0);
        acc11 = __builtin_amdgcn_mfma_f32_16x16x32_bf16(a1,b1,acc11,0,0,0);
        __syncthreads();
    }
    #pragma unroll
    for (int i=0;i<2;i++){
        int rowb = m0 + wm*32 + i*16 + q*4;
        #pragma unroll
        for (int j=0;j<2;j++){
            int col = n0 + wn*32 + j*16 + l16;
            f32x4 av2 = (i==0) ? ((j==0)?acc00:acc01) : ((j==0)?acc10:acc11);
            #pragma unroll
            for (int r=0;r<4;r++){
                int row = rowb + r;
                u16 o = f2bf(av2[r]);
                if (swz) C[swzE(row,col)] = o;
                else     C[(size_t)row*HID + col] = o;
            }
        }
    }
}
// 64x64-tile GEMM, fp32 out, row guard, optional column-vector add; same prefetch.
// atom=1 -> atomicAdd into pre-zeroed C (split-K use)
__device__ __forceinline__ void gemm64f(int bx, int by, const u16* __restrict__ A, int lda,
                                        const u16* __restrict__ Bt, int ldb,
                                        float* __restrict__ C, int M, int K,
                                        const float* __restrict__ addv, int atom, char* smem)
{
    u16* As = (u16*)smem;
    u16* Bs = (u16*)smem + 64*40;
    const int tid = threadIdx.x;
    const int wave = tid>>6, lane = tid&63;
    const int wm = wave>>1, wn = wave&1;
    const int q = lane>>4, l16 = lane&15;
    const int m0 = bx*64, n0 = by*64;
    const int sm = tid>>2, sk = (tid&3)*8;
    f32x4 acc00={0,0,0,0}, acc01={0,0,0,0}, acc10={0,0,0,0}, acc11={0,0,0,0};
    const bool aOk = (m0+sm) < M;
    const u16* Ap = A + (size_t)(m0+sm)*lda + sk;
    const u16* Bp = Bt + (size_t)(n0+sm)*ldb + sk;
    short8 av = {0,0,0,0,0,0,0,0};
    if (aOk) av = *(const short8*)(Ap);
    short8 bv = *(const short8*)(Bp);
    for (int k0=0; k0<K; k0+=32){
        *(short8*)(As + sm*40 + sk) = av;
        *(short8*)(Bs + sm*40 + sk) = bv;
        __syncthreads();
        if (k0+32 < K){
            if (aOk) av = *(const short8*)(Ap + k0 + 32);
            bv = *(const short8*)(Bp + k0 + 32);
        }
        short8 a0 = *(const short8*)(As + (wm*32      + l16)*40 + q*8);
        short8 a1 = *(const short8*)(As + (wm*32 + 16 + l16)*40 + q*8);
        short8 b0 = *(const short8*)(Bs + (wn*32      + l16)*40 + q*8);
        short8 b1 = *(const short8*)(Bs + (wn*32 + 16 + l16)*40 + q*8);
        acc00 = __builtin_amdgcn_mfma_f32_16x16x32_bf16(a0,b0,acc00,0,0,0);
        acc01 = __builtin_amdgcn_mfma_f32_16x16x32_bf16(a0,b1,acc01,0,0,0);
        acc10 = __builtin_amdgcn_mfma_f32_16x16x32_bf16(a1,b0,acc10,0,0,0);
        acc11 = __builtin_amdgcn_mfma_f32_16x16x32_bf16(a1,b1,acc11,0,0,0);
        __syncthreads();
    }
    #pragma unroll
    for (int i=0;i<2;i++){
        int rowb = m0 + wm*32 + i*16 + q*4;
        #pragma unroll
        for (int j=0;j<2;j++){
            int col = n0 + wn*32 + j*16 + l16;
            f32x4 av2 = (i==0) ? ((j==0)?acc00:acc01) : ((j==0)?acc10:acc11);
            float add = addv ? addv[col] : 0.f;
            #pragma unroll
            for (int r=0;r<4;r++){
                int row = rowb + r;
                if (row < M){
                    float v = av2[r] + add;
                    if (atom) atomicAdd(&C[(size_t)row*HID + col], v);
                    else      C[(size_t)row*HID + col] = v;
                }
            }
        }
    }
}
// bf16 transpose tile (src[R=2560 rows? generic], here fuseW [2560,960] -> fuseWT [960,2560])
__device__ __forceinline__ void transpose_tile(int bx, int by, const u16* __restrict__ src,
                                               u16* __restrict__ dst, int R, int C, char* smem)
{
    u16 (*tl)[33] = (u16(*)[33])smem;
    int c0 = bx*32, r0 = by*32;
    int tx = threadIdx.x & 31, ty = threadIdx.x >> 5;   // 32x8
    #pragma unroll
    for (int i=0;i<4;i++) tl[ty+i*8][tx] = src[(size_t)(r0+ty+i*8)*C + c0+tx];
    __syncthreads();
    #pragma unroll
    for (int i=0;i<4;i++) dst[(size_t)(c0+ty+i*8)*R + r0+tx] = tl[tx][ty+i*8];
}
// split-K vec-mat, += into pre-zeroed out
__device__ __forceinline__ void vecmat_body(int bx, int by, const float* __restrict__ v,
                                            const u16* __restrict__ M, float* __restrict__ out, char* smem)
{
    float (*part)[64] = (float(*)[64])smem;
    int tid = threadIdx.x;
    int cl = tid & 63;
    int c = bx*64 + cl;
    int kg = tid >> 6;
    int k0 = by*60 + kg*15;
    float s = 0.f;
    #pragma unroll
    for (int i=0;i<15;i++) s += v[k0+i]*bf2f(M[(size_t)(k0+i)*HID + c]);
    part[kg][cl] = s;
    __syncthreads();
    if (kg==0) atomicAdd(&out[c], part[0][cl]+part[1][cl]+part[2][cl]+part[3][cl]);
}
// 256-thread scan + dinv
__device__ __forceinline__ void scandinv_body(const int* __restrict__ deg, int* __restrict__ off,
                                              int* __restrict__ cur, float* __restrict__ dinv, char* smem)
{
    int* ps = (int*)smem;
    int t = threadIdx.x;
    const int chunk = N_NODES/256; // 64
    int base0 = t*chunk;
    int s = 0;
    for (int i=0;i<chunk;i++) s += deg[base0+i];
    ps[t] = s; __syncthreads();
    for (int ofs=1; ofs<256; ofs<<=1){
        int v = ps[t];
        int add = (t>=ofs) ? ps[t-ofs] : 0;
        __syncthreads();
        ps[t] = v + add;
        __syncthreads();
    }
    int run = (t==0) ? 0 : ps[t-1];
    for (int i=0;i<chunk;i++){
        int d = deg[base0+i];
        off[base0+i]=run; cur[base0+i]=run; run += d;
        dinv[base0+i] = rsqrtf(1.0f + (float)d);
    }
    if (t==255) off[N_NODES] = run;
}

// ================= fused selector kernels =================
// L1: fuseW transpose (2400 blocks) + hist (256)
__global__ __launch_bounds__(256) void k_L1(const u16* __restrict__ fuseWn, u16* __restrict__ fuseWT,
                                            const int* __restrict__ dst, int* __restrict__ deg){
    __shared__ __attribute__((aligned(16))) char smem[2112];
    int b = blockIdx.x;
    if (b < 2400){
        transpose_tile(b%30, b/30, fuseWn, fuseWT, 2560, HID, smem);
    } else {
        int e = (b-2400)*256 + threadIdx.x;
        if (e < E_EDGES) atomicAdd(&deg[dst[e]], 1);
    }
}
// L2: gemmS pair (Ub, WglobT) (450) + scandinv (1)
__global__ __launch_bounds__(256) void k_L2(const u16* fuseWT, const u16* projWn, const u16* W2n,
                                            u16* Ub, u16* WglobT,
                                            const int* deg, int* off, int* cur, float* dinv){
    __shared__ __attribute__((aligned(16))) char smem[10240];
    int b = blockIdx.x;
    if (b < 450){
        int z = b/225, r = b%225;
        if (z==0) gemm_sq(r%15, r/15, fuseWT+640, 2560, projWn, HID, Ub, 0, smem);
        else      gemm_sq(r%15, r/15, fuseWT+1600, 2560, W2n, HID, WglobT, 0, smem);
    } else {
        scandinv_body(deg, off, cur, dinv, smem);
    }
}
// L3: WbigS = (Ub @ W2^T) swizzled (225) + gemmB fgA/pWbM (75) + scatter (256)
__global__ __launch_bounds__(256) void k_L3(const u16* Ub, const u16* W2n, u16* WbigS,
                                            const u16* fgeN, const u16* posN, const u16* fuseWT,
                                            float* fgA, float* pWbM,
                                            const int* src, const int* dst, const float* dinv,
                                            int* cur, int* csr_s, float* csr_w){
    __shared__ __attribute__((aligned(16))) char smem[10240];
    int b = blockIdx.x;
    if (b < 225){
        gemm_sq(b%15, b/15, Ub, HID, W2n, HID, WbigS, 1, smem);
    } else if (b < 300){
        int bb = b-225;
        if (bb < 60) gemm64f(bb%4, bb/4, fgeN, 512, fuseWT, 2560, fgA, NFG, 512, nullptr, 0, smem);
        else         gemm64f(0, bb-60, posN, 128, fuseWT+512, 2560, pWbM, FMAXF, 128, nullptr, 0, smem);
    } else {
        int e = (b-300)*256 + threadIdx.x;
        if (e < E_EDGES){
            int s = src[e], d = dst[e];
            int p = atomicAdd(&cur[d], 1);
            csr_s[p] = s;
            csr_w[p] = dinv[s]*dinv[d];
        }
    }
}
// L4: fused aggx+h1 (8192 blocks, 2 nodes each) + vecmat3 (720)
__global__ __launch_bounds__(256) void k_L4(const u16* __restrict__ gxn, const float* __restrict__ dinv,
                                            const int* __restrict__ off, const int* __restrict__ csr_s,
                                            const float* __restrict__ csr_w,
                                            const u16* __restrict__ W1, const u16* __restrict__ b1,
                                            u16* __restrict__ h1b,
                                            const float* b2f, const float* projbf, const u16* fuseWn,
                                            const u16* projWn, float* tvb, float* cC, float* gvec){
    __shared__ __attribute__((aligned(16))) char smem[1024];
    int b = blockIdx.x;
    if (b < 8192){
        float* a2 = (float*)smem;     // [2][8]
        int t = threadIdx.x;
        int h = t>>7, tl = t&127;
        int n = b*2 + h;
        if (tl < 5){
            int k = tl;
            float di = dinv[n], sw = di*di;
            float a = sw * bf2f(gxn[n*5+k]);
            int j0 = off[n], j1 = off[n+1];
            int j = j0;
            // batch-4 neighbor processing for MLP (order preserved)
            for (; j+4<=j1; j+=4){
                int   s0=csr_s[j],   s1=csr_s[j+1],   s2=csr_s[j+2],   s3=csr_s[j+3];
                float w0=csr_w[j],   w1=csr_w[j+1],   w2=csr_w[j+2],   w3=csr_w[j+3];
                float g0=bf2f(gxn[s0*5+k]), g1=bf2f(gxn[s1*5+k]);
                float g2=bf2f(gxn[s2*5+k]), g3=bf2f(gxn[s3*5+k]);
                a += w0*g0; a += w1*g1; a += w2*g2; a += w3*g3;
            }
            for (; j<j1; j++) a += csr_w[j]*bf2f(gxn[csr_s[j]*5+k]);
            a2[h*8+k] = a;
        }
        __syncthreads();
        if (tl < 120){
            int c8 = tl*8;
            float a[5];
            #pragma unroll
            for (int k=0;k<5;k++) a[k] = a2[h*8+k];
            float r[8];
            short8 bb = *(const short8*)(b1 + c8);
            #pragma unroll
            for (int j=0;j<8;j++) r[j] = bf2f(((u16*)&bb)[j]);
            #pragma unroll
            for (int k=0;k<5;k++){
                short8 wv = *(const short8*)(W1 + k*HID + c8);
                #pragma unroll
                for (int j=0;j<8;j++) r[j] += a[k]*bf2f(((u16*)&wv)[j]);
            }
            short8 o;
            #pragma unroll
            for (int j=0;j<8;j++) ((u16*)&o)[j] = f2bf(fmaxf(r[j],0.f));
            *(short8*)(h1b + (size_t)n*HID + c8) = o;
        }
    } else {
        int bb = b - 8192;
        int z = bb/240, r = bb%240;
        if (z==0)      vecmat_body(r%15, r/15, b2f,    projWn,            tvb,  smem);
        else if (z==1) vecmat_body(r%15, r/15, projbf, fuseWn + 640*HID,  cC,   smem);
        else           vecmat_body(r%15, r/15, b2f,    fuseWn + 1600*HID, gvec, smem);
    }
}
// L5: p1 column-sliced XCD-pinned (16384) + vecmat vb (240) + addc c0 (4) + zero Gc (240)
// p1: HID split into 8 slices of 120 cols; slice = b%8 pins each slice to one XCD
// (same mapping heuristic validated by R7's L6 win). Touched slice working set =
// 16384 rows x 240 B = 3.93 MB <= 4 MB per-XCD L2, so the ~15.7 MB of random
// neighbor slice-reads per XCD hit a resident footprint instead of thrashing the
// whole 30 MB h1b through L3 (~13% hit rate before). Per-column accumulation
// order unchanged -> bit-exact. Block = 8 nodes x 32 threads (15 active x short8).
__global__ __launch_bounds__(256) void k_L5(const u16* __restrict__ h1b, const float* __restrict__ dinv,
                                            const int* __restrict__ off, const int* __restrict__ csr_s,
                                            const float* __restrict__ csr_w, u16* __restrict__ P1b,
                                            const float* tvb, const u16* fuseWn, float* vb,
                                            const float* cC, const float* gvec, const u16* fusebn, float* c0,
                                            float* __restrict__ Gc){
    __shared__ __attribute__((aligned(16))) char smem[1024];
    int b = blockIdx.x;
    if (b < 16384){
        int slice = b & 7;
        int ng = b >> 3;                        // node group [0,2048)
        int t = threadIdx.x & 31;
        int n = ng*8 + (threadIdx.x >> 5);
        bool act = t < 15;
        int c = slice*120 + t*8;
        float di = dinv[n], sw = di*di;
        float acc[8];
        if (act){
            short8 h0 = *(const short8*)(h1b + (size_t)n*HID + c);
            #pragma unroll
            for (int j=0;j<8;j++) acc[j] = sw*bf2f(((u16*)&h0)[j]);
        } else {
            #pragma unroll
            for (int j=0;j<8;j++) acc[j] = 0.f;
        }
        int j0 = off[n], j1 = off[n+1];
        int j = j0;
        for (; j+4<=j1; j+=4){
            int   s0=csr_s[j],   s1=csr_s[j+1],   s2=csr_s[j+2],   s3=csr_s[j+3];
            float w0=csr_w[j],   w1=csr_w[j+1],   w2=csr_w[j+2],   w3=csr_w[j+3];
            if (act){
                short8 a0 = *(const short8*)(h1b + (size_t)s0*HID + c);
                short8 a1 = *(const short8*)(h1b + (size_t)s1*HID + c);
                short8 a2 = *(const short8*)(h1b + (size_t)s2*HID + c);
                short8 a3 = *(const short8*)(h1b + (size_t)s3*HID + c);
                #pragma unroll
                for (int j2=0;j2<8;j2++) acc[j2] += w0*bf2f(((u16*)&a0)[j2]);
                #pragma unroll
                for (int j2=0;j2<8;j2++) acc[j2] += w1*bf2f(((u16*)&a1)[j2]);
                #pragma unroll
                for (int j2=0;j2<8;j2++) acc[j2] += w2*bf2f(((u16*)&a2)[j2]);
                #pragma unroll
                for (int j2=0;j2<8;j2++) acc[j2] += w3*bf2f(((u16*)&a3)[j2]);
            }
        }
        for (; j<j1; j++){
            int s = csr_s[j]; float w = csr_w[j];
            if (act){
                short8 v0 = *(const short8*)(h1b + (size_t)s*HID + c);
                #pragma unroll
                for (int j2=0;j2<8;j2++) acc[j2] += w*bf2f(((u16*)&v0)[j2]);
            }
        }
        if (act){
            short8 o0;
            #pragma unroll
            for (int j2=0;j2<8;j2++) ((u16*)&o0)[j2] = f2bf(acc[j2]);
            *(short8*)(P1b + (size_t)n*HID + c) = o0;
        }
    } else if (b < 16624){
        int bb = b - 16384;
        vecmat_body(bb%15, bb/15, tvb, fuseWn + 640*HID, vb, smem);
    } else if (b < 16628){
        int c = (b-16624)*256 + threadIdx.x;
        if (c < HID) c0[c] = cC[c] + gvec[c] + bf2f(fusebn[c]);
    } else {
        int id = (b-16628)*256 + threadIdx.x;   // 240*256 = 61440 = (256*960)/4
        *(f32x4*)(Gc + (size_t)id*4) = (f32x4){0.f,0.f,0.f,0.f};
    }
}
// L6: pr (2048, XCD-chunk-swizzled) + gm split-2 (240)
// pr: XCD swizzle (work = (b%8)*256 + b/8, bijective since 2048%8==0) groups the 8
// blocks of each molecule (120 KB P1b window) onto ONE XCD; each XCD's chunk covers
// 32 molecules = 3.84 MB — fits its 4 MB private L2. (R7: −14 µs.)
// Indices preloaded via 4x int4 for MLP (R6).
__global__ __launch_bounds__(256) void k_L6(const u16* __restrict__ P1b, const int* __restrict__ fgi,
                                            const int* __restrict__ ptr, u16* __restrict__ prb,
                                            float* __restrict__ evec, u16* __restrict__ maskb,
                                            float* __restrict__ maskf, const int* __restrict__ flag,
                                            u16* __restrict__ gmb){
    int b = blockIdx.x;
    if (b < 2048){
        int wb = (b&7)*256 + (b>>3);           // XCD-chunked work id
        int wv = threadIdx.x>>6, lane = threadIdx.x&63;
        int bf = wb*4 + wv;
        int mb = bf >> 5;
        int base = ptr[mb];
        int c = lane*16;
        bool act = lane < 60;
        // preload all 16 indices (64 B, wave-uniform broadcast)
        const int4* fp4 = (const int4*)(fgi + bf*AMAXA);
        int4 q0 = fp4[0], q1 = fp4[1], q2 = fp4[2], q3 = fp4[3];
        int idxv[16] = {q0.x,q0.y,q0.z,q0.w, q1.x,q1.y,q1.z,q1.w,
                        q2.x,q2.y,q2.z,q2.w, q3.x,q3.y,q3.z,q3.w};
        int cnt = 0;
        #pragma unroll
        for (int a=0;a<AMAXA;a++) cnt += (idxv[a] >= 0) ? 1 : 0;
        float acc[16];
        #pragma unroll
        for (int j=0;j<16;j++) acc[j] = 0.f;
        #pragma unroll
        for (int a=0;a<AMAXA;a++){
            int idx = idxv[a];
            if (idx >= 0 && act){
                const u16* rp = P1b + (size_t)(base+idx)*HID + c;
                short8 v0 = *(const short8*)(rp);
                short8 v1 = *(const short8*)(rp + 8);
                #pragma unroll
                for (int j=0;j<8;j++){ acc[j] += bf2f(((u16*)&v0)[j]); acc[8+j] += bf2f(((u16*)&v1)[j]); }
            }
        }
        float inv = (cnt>0) ? 1.0f/(float)cnt : 0.0f;
        if (act){
            short8 o0, o1;
            #pragma unroll
            for (int j=0;j<8;j++){ ((u16*)&o0)[j] = f2bf(acc[j]*inv); ((u16*)&o1)[j] = f2bf(acc[8+j]*inv); }
            *(short8*)(prb + swzA(bf, c)) = o0;
            *(short8*)(prb + swzA(bf, c+8)) = o1;
        }
        if (lane == 0){
            float e = (cnt>0) ? 1.0f : 0.0f;
            evec[bf] = e;
            if (*flag) maskf[bf] = e;
            else       maskb[bf] = f2bf(e);
        }
    } else {
        // gm: 240 blocks; 2 threads per (mol, c8) item, 32 nodes each, pair-combine
        int bb = b - 2048;
        int idt = bb*256 + threadIdx.x;        // < 61440
        int item = idt >> 1, half = idt & 1;   // item < 30720 = 256*120
        int mb = item / 120; int c8 = (item - mb*120)*8;
        const u16* Pp = P1b + (size_t)(mb*NPM + half*32)*HID + c8;
        float s[8] = {0,0,0,0,0,0,0,0};
        for (int i=0;i<32;i++){
            short8 v = *(const short8*)(Pp + (size_t)i*HID);
            #pragma unroll
            for (int j=0;j<8;j++) s[j] += bf2f(((u16*)&v)[j]);
        }
        #pragma unroll
        for (int j=0;j<8;j++) s[j] += __shfl_xor(s[j], 1, 64);
        if (half == 0){
            const float inv = 1.0f/(float)NPM;
            short8 o;
            #pragma unroll
            for (int j=0;j<8;j++) ((u16*)&o)[j] = f2bf(s[j]*inv);
            *(short8*)(gmb + (size_t)mb*HID + c8) = o;
        }
    }
}
// L7: Gc += gm @ WglobT^T (+c0 on first half), split-K2 atomic into pre-zeroed Gc (120 blocks)
__global__ __launch_bounds__(256) void k_L7(const u16* gmb, const u16* WglobT, float* Gc, const float* c0){
    __shared__ __attribute__((aligned(16))) char smem[10240];
    int b = blockIdx.x;
    int z = b/60, r = b%60;
    gemm64f(r%4, r/4, gmb + z*480, HID, WglobT + z*480, HID, Gc, B_MOL, 480,
            z ? nullptr : c0, 1, smem);
}

// L8 final GEMM: out[8192,960] = prb @ WbigS^T + epilogue
// BM=128, BN=96, BK=32; 8 waves (512 threads) — each wave computes a 32x48
// sub-tile (2x3 frags). TRIPLE-buffered staging, depth-2 prefetch with COUNTED vmcnt:
// waves 0-6 each stage 2 regions/stage (steady-state vmcnt(2)), wave 7 stages nothing.
// Epilogue: i-outer/j-inner (j-outer caused partial-cacheline RMW, R2). grid 64x10=640
__global__ __launch_bounds__(512) void k_gemmF(
    const u16* __restrict__ A, const u16* __restrict__ Bt,
    float* __restrict__ Cf, u16* __restrict__ Cb,
    const int* __restrict__ fg_type, const float* __restrict__ evec,
    const float* __restrict__ fgA, const float* __restrict__ pWbM,
    const float* __restrict__ vb, const float* __restrict__ Gc,
    const int* __restrict__ flag)
{
    __shared__ __attribute__((aligned(16))) u16 S[3][14*512];   // A regions 0..7, B regions 8..13
    const int tid = threadIdx.x;
    const int wave = tid>>6, lane = tid&63;
    const int wm = wave&3, wn = wave>>2;        // 4 row-groups x 2 col-groups
    const int q = lane>>4, l16 = lane&15;
    const int m0 = blockIdx.x*128, n0 = blockIdx.y*96;
    const int R0 = blockIdx.x*8, N0 = blockIdx.y*6;

    f32x4 acc[2][3];
    #pragma unroll
    for (int i=0;i<2;i++)
        #pragma unroll
        for (int j=0;j<3;j++) acc[i][j] = (f32x4){0,0,0,0};

    // staging: wave w (w<7) owns regions 2w and 2w+1 (regions 0..7 = A rows, 8..13 = B cols)
    const int r0 = wave*2, r1 = wave*2+1;
    const bool stager = (wave < 7);
    const u16* gP0 = (r0 < 8) ? A  + ((size_t)(R0 + r0    )*30)*512 + lane*8
                              : Bt + ((size_t)(N0 + r0 - 8)*30)*512 + lane*8;
    const u16* gP1 = (r1 < 8) ? A  + ((size_t)(R0 + r1    )*30)*512 + lane*8
                              : Bt + ((size_t)(N0 + r1 - 8)*30)*512 + lane*8;

    u16* sA = &S[0][0];
    u16* sB = &S[1][0];
    u16* sC = &S[2][0];

    // prologue: stage 0 and 1; wait stage 0 complete (stage 1 stays in flight)
    if (stager){
        gload_lds16(gP0,        sA + r0*512);
        gload_lds16(gP1,        sA + r1*512);
        gload_lds16(gP0 + 512,  sB + r0*512);
        gload_lds16(gP1 + 512,  sB + r1*512);
        asm volatile("s_waitcnt vmcnt(2)" ::: "memory");
    }
    __builtin_amdgcn_s_barrier();

    for (int kc=0; kc<30; kc++){
        // issue stage kc+2 into sC (buffer last read at iter kc-1; a barrier intervened)
        if (stager && kc+2 < 30){
            const int kn = (kc+2)*512;
            gload_lds16(gP0 + kn, sC + r0*512);
            gload_lds16(gP1 + kn, sC + r1*512);
        }
        // compute from sA (stage kc — complete per last barrier's preceding vmcnt)
        short8 af[2], bfr[3];
        #pragma unroll
        for (int i=0;i<2;i++) af[i] = *(const short8*)(sA + (wm*2+i)*512 + lane*8);
        #pragma unroll
        for (int j=0;j<3;j++) bfr[j] = *(const short8*)(sA + (8+wn*3+j)*512 + lane*8);
        __builtin_amdgcn_s_setprio(1);
        #pragma unroll
        for (int i=0;i<2;i++)
            #pragma unroll
            for (int j=0;j<3;j++)
                acc[i][j] = __builtin_amdgcn_mfma_f32_16x16x32_bf16(af[i], bfr[j], acc[i][j], 0,0,0);
        __builtin_amdgcn_s_setprio(0);
        if (kc < 29){
            if (stager){
                if (kc < 28) asm volatile("s_waitcnt vmcnt(2)" ::: "memory");  // kc+1 done, kc+2 in flight
                else         asm volatile("s_waitcnt vmcnt(0)" ::: "memory");  // drain last stage
            }
            __builtin_amdgcn_s_barrier();
        }
        // rotate buffers
        u16* t = sA; sA = sB; sB = sC; sC = t;
    }

    const int isf = *flag;
    #pragma unroll
    for (int i=0;i<2;i++){
        int rowb = m0 + wm*32 + i*16 + q*4;
        #pragma unroll
        for (int r=0;r<4;r++){
            int row = rowb + r;
            int bb = row>>5, ff = row&31;
            int ty = fg_type[row];
            float e = evec[row];
            #pragma unroll
            for (int j=0;j<3;j++){
                int col = n0 + wn*48 + j*16 + l16;
                float v = acc[i][j][r]
                        + fgA[(size_t)ty*HID+col] + pWbM[ff*HID+col]
                        + e*vb[col] + Gc[(size_t)bb*HID+col];
                if (isf) Cf[(size_t)row*HID + col] = v;
                else     Cb[(size_t)row*HID + col] = f2bf(v);
            }
        }
    }
}

extern "C" void kernel_launch(void* const* d_in, const int* in_sizes, int n_in,
                              void* d_out, int out_size, void* d_ws, size_t ws_size,
                              hipStream_t stream) {
    const int* edge_idx  = (const int*)d_in[1];
    const int* ptr       = (const int*)d_in[3];
    const int* fg_type   = (const int*)d_in[4];
    const int* fg_idx    = (const int*)d_in[5];

    // ---- workspace layout ----
    char* w = (char*)d_ws;
    auto nxt = [&](size_t b)->char*{ char* p = w; w += (b + 255) & ~(size_t)255; return p; };
    u16* big0   = (u16*)nxt((size_t)N_NODES*HID*2);       // fuseWT+Ub -> h1b -> prb(swizzled)
    u16* fuseWT = big0;
    u16* Ub     = big0 + (size_t)HID*2560;
    u16* h1b    = big0;
    u16* prb    = big0;
    u16* P1b    = (u16*)nxt((size_t)N_NODES*HID*2);
    u16*  WbigS  = (u16*) nxt((size_t)HID*HID*2);
    u16*  WglobT = (u16*) nxt((size_t)HID*HID*2);
    float* fgA   = (float*)nxt((size_t)NFG*HID*4);
    float* pWbM  = (float*)nxt((size_t)FMAXF*HID*4);
    float* b2f   = (float*)nxt(HID*4);
    float* projbf= (float*)nxt(HID*4);
    float* tvb   = (float*)nxt(HID*4);   // tvb,cC,gvec,vb contiguous zero-block of 4*HID
    float* cC    = (float*)nxt(HID*4);
    float* gvec  = (float*)nxt(HID*4);
    float* vb    = (float*)nxt(HID*4);
    float* c0    = (float*)nxt(HID*4);
    int*   deg   = (int*)  nxt(N_NODES*4);
    float* dinv  = (float*)nxt(N_NODES*4);
    int*   off   = (int*)  nxt((N_NODES+1)*4);
    int*   cur   = (int*)  nxt(N_NODES*4);
    int*   csr_s = (int*)  nxt(E_EDGES*4);
    float* csr_w = (float*)nxt(E_EDGES*4);
    float* evec  = (float*)nxt(BF_ROWS*4);
    u16*   gmb   = (u16*)  nxt((size_t)B_MOL*HID*2);
    float* Gc    = (float*)nxt((size_t)B_MOL*HID*4);
    int*   flag  = (int*)  nxt(256);
    u16*   region= (u16*)  nxt((size_t)NTOT*2);
    // views into region
    u16* gxn    = region;
    u16* W1n    = region +   81920;
    u16* b1n    = region +   86720;
    u16* W2n    = region +   87680;
    u16* fgeN   = region + 1010240;
    u16* posN   = region + 1115200;
    u16* projWn = region + 1135680;
    u16* fuseWn = region + 2058240;
    u16* fusebn = region + 4515840;

    NormSrcs ns;
    ns.p[0]=d_in[0]; ns.p[1]=d_in[6]; ns.p[2]=d_in[7]; ns.p[3]=d_in[8]; ns.p[4]=d_in[9];
    ns.p[5]=d_in[10]; ns.p[6]=d_in[11]; ns.p[7]=d_in[12]; ns.p[8]=d_in[13]; ns.p[9]=d_in[14]; ns.p[10]=d_in[15];
    // L0: normalize (+flag, +b2f/projbf, zero deg and tvb..vb), 8 elems/thread
    k_normAll<<<(NTOT/8+255)/256,256,0,stream>>>(ns, region, b2f, projbf, tvb, flag, deg);
    // L1: transpose fuseW + hist
    k_L1<<<2656,256,0,stream>>>(fuseWn, fuseWT, edge_idx + E_EDGES, deg);
    // L2: Ub, WglobT + scan/dinv
    k_L2<<<451,256,0,stream>>>(fuseWT, projWn, W2n, Ub, WglobT, deg, off, cur, dinv);
    // L3: WbigS(swz) + fgA/pWbM + scatter
    k_L3<<<556,256,0,stream>>>(Ub, W2n, WbigS, fgeN, posN, fuseWT, fgA, pWbM,
                               edge_idx, edge_idx + E_EDGES, dinv, cur, csr_s, csr_w);
    // L4: aggx+h1 fused + vecmat3 (tvb,cC,gvec)
    k_L4<<<8912,256,0,stream>>>(gxn, dinv, off, csr_s, csr_w, W1n, b1n, h1b,
                                b2f, projbf, fuseWn, projWn, tvb, cC, gvec);
    // L5: p1 (column-sliced, XCD-pinned) + vecmat(vb) + addc(c0) + zero Gc
    k_L5<<<16868,256,0,stream>>>(h1b, dinv, off, csr_s, csr_w, P1b,
                                 tvb, fuseWn, vb, cC, gvec, fusebn, c0, Gc);
    // L6: pr (swizzled prb + mask, XCD-chunked) + gm (split-2, 240 blocks)
    k_L6<<<2288,256,0,stream>>>(P1b, fg_idx, ptr, prb, evec,
                                (u16*)d_out + OUT1, (float*)d_out + OUT1, flag, gmb);
    // L7: Gc = gm @ (W2 Wd) + c0, split-K2 atomic (120 blocks)
    k_L7<<<120,256,0,stream>>>(gmb, WglobT, Gc, c0);
    // L8: final GEMM + epilogue (512 threads, 8 waves)
    k_gemmF<<<dim3(64,10),512,0,stream>>>(prb, WbigS, (float*)d_out, (u16*)d_out,
                                          fg_type, evec, fgA, pWbM, vb, Gc, flag);
    (void)in_sizes; (void)n_in; (void)out_size; (void)ws_size;
}

// Round 9
// 246.018 us; speedup vs baseline: 1.0644x; 1.0644x over previous
//
#include <hip/hip_runtime.h>

typedef unsigned short u16;
typedef unsigned int u32;
typedef __attribute__((ext_vector_type(8))) short short8;
typedef __attribute__((ext_vector_type(4))) float f32x4;

#define N_NODES 16384
#define B_MOL   256
#define NPM     64
#define E_EDGES 65536
#define FMAXF   32
#define AMAXA   16
#define HID     960
#define NFG     205
#define BF_ROWS 8192
#define OUT1    7864320   // B*FMAX*HID
#define NTOT    4516800   // total normalized elements

__device__ __forceinline__ float bf2f(u16 u){ u32 x=((u32)u)<<16; float f; __builtin_memcpy(&f,&x,4); return f; }
__device__ __forceinline__ u16 f2bf(float f){ u32 x; __builtin_memcpy(&x,&f,4); x += 0x7FFFu + ((x>>16)&1u); return (u16)(x>>16); }

__device__ __forceinline__ void gload_lds16(const u16* g, u16* l){
    __builtin_amdgcn_global_load_lds(
        (const __attribute__((address_space(1))) void*)g,
        (__attribute__((address_space(3))) void*)l, 16, 0, 0);
}
// swizzled fragment-region address (16-row x 32-col regions of a 960-col matrix)
__device__ __forceinline__ size_t swzA(int row, int col){      // col multiple of 8, u16 units
    return ((size_t)((row>>4)*30 + (col>>5)))*512 + (size_t)(((((col>>3)&3)*16) + (row&15))*8);
}
__device__ __forceinline__ size_t swzE(int row, int col){      // element-granular
    return ((size_t)((row>>4)*30 + (col>>5)))*512 + (size_t)((((col>>3)&3)*16 + (row&15))*8 + (col&7));
}

struct NormSrcs { const void* p[11]; };
// all 11 float tensors -> contiguous bf16 region; 8 elements per thread (all segment
// boundaries are multiples of 8). per-block dtype flag; b2f/projbf fp32; zero deg + bias-accum
__global__ __launch_bounds__(256) void k_normAll(NormSrcs s, u16* __restrict__ region,
                                                 float* __restrict__ b2f, float* __restrict__ projbf,
                                                 float* __restrict__ z4, int* __restrict__ flag,
                                                 int* __restrict__ deg){
    __shared__ int cnt;
    int t = threadIdx.x;
    if (t==0) cnt = 0;
    __syncthreads();
    u16 pv = ((const u16*)s.p[0])[t*2];
    if (((pv>>7)&0xFF) >= 0xC0) atomicAdd(&cnt, 1);
    __syncthreads();
    int fl = (cnt > 16) ? 1 : 0;              // 1 => inputs are fp32
    int gid = blockIdx.x*256 + t;
    if (blockIdx.x==0 && t==0) *flag = fl;
    int base = gid*8;
    const f32x4 zf = {0.f,0.f,0.f,0.f};
    if (base < N_NODES){ *(f32x4*)(deg+base) = zf; *(f32x4*)(deg+base+4) = zf; }
    if (base < 4*HID)  { *(f32x4*)(z4+base)  = zf; *(f32x4*)(z4+base+4)  = zf; }
    if (base >= NTOT) return;
    int seg, off;
    if      (base <   81920){seg=0;  off=base;}
    else if (base <   86720){seg=1;  off=base-81920;}
    else if (base <   87680){seg=2;  off=base-86720;}
    else if (base < 1009280){seg=3;  off=base-87680;}
    else if (base < 1010240){seg=4;  off=base-1009280;}
    else if (base < 1115200){seg=5;  off=base-1010240;}
    else if (base < 1135680){seg=6;  off=base-1115200;}
    else if (base < 2057280){seg=7;  off=base-1135680;}
    else if (base < 2058240){seg=8;  off=base-2057280;}
    else if (base < 4515840){seg=9;  off=base-2058240;}
    else                    {seg=10; off=base-4515840;}
    const void* sp = s.p[seg];
    short8 ov;
    float fvs[8];
    if (fl){
        const float* fp = (const float*)sp + off;
        f32x4 v0 = *(const f32x4*)(fp);
        f32x4 v1 = *(const f32x4*)(fp+4);
        #pragma unroll
        for (int j=0;j<4;j++){ fvs[j]=v0[j]; fvs[4+j]=v1[j]; }
        #pragma unroll
        for (int j=0;j<8;j++) ((u16*)&ov)[j] = f2bf(fvs[j]);
    } else {
        ov = *(const short8*)((const u16*)sp + off);
        #pragma unroll
        for (int j=0;j<8;j++) fvs[j] = bf2f(((u16*)&ov)[j]);
    }
    *(short8*)(region + base) = ov;
    if (seg==4){
        *(f32x4*)(b2f+off)   = (f32x4){fvs[0],fvs[1],fvs[2],fvs[3]};
        *(f32x4*)(b2f+off+4) = (f32x4){fvs[4],fvs[5],fvs[6],fvs[7]};
    }
    if (seg==8){
        *(f32x4*)(projbf+off)   = (f32x4){fvs[0],fvs[1],fvs[2],fvs[3]};
        *(f32x4*)(projbf+off+4) = (f32x4){fvs[4],fvs[5],fvs[6],fvs[7]};
    }
}

// ================= device bodies (parameterized by block coords + smem) =================

// square-960 bf16 GEMM: C = A @ Bt^T (bf16 out; optional swizzled store)
// register-staged prefetch: next k-chunk issued right after the top barrier.
__device__ __forceinline__ void gemm_sq(int bx, int by, const u16* __restrict__ A, int lda,
                                        const u16* __restrict__ Bt, int ldb,
                                        u16* __restrict__ C, int swz, char* smem)
{
    u16* As = (u16*)smem;            // 64*40
    u16* Bs = (u16*)smem + 64*40;
    const int tid = threadIdx.x;
    const int wave = tid>>6, lane = tid&63;
    const int wm = wave>>1, wn = wave&1;
    const int q = lane>>4, l16 = lane&15;
    const int m0 = bx*64, n0 = by*64;
    const int sm = tid>>2, sk = (tid&3)*8;
    f32x4 acc00={0,0,0,0}, acc01={0,0,0,0}, acc10={0,0,0,0}, acc11={0,0,0,0};
    const u16* Ap = A + (size_t)(m0+sm)*lda + sk;
    const u16* Bp = Bt + (size_t)(n0+sm)*ldb + sk;
    short8 av = *(const short8*)(Ap);
    short8 bv = *(const short8*)(Bp);
    for (int k0=0; k0<HID; k0+=32){
        *(short8*)(As + sm*40 + sk) = av;
        *(short8*)(Bs + sm*40 + sk) = bv;
        __syncthreads();
        if (k0+32 < HID){
            av = *(const short8*)(Ap + k0 + 32);
            bv = *(const short8*)(Bp + k0 + 32);
        }
        short8 a0 = *(const short8*)(As + (wm*32      + l16)*40 + q*8);
        short8 a1 = *(const short8*)(As + (wm*32 + 16 + l16)*40 + q*8);
        short8 b0 = *(const short8*)(Bs + (wn*32      + l16)*40 + q*8);
        short8 b1 = *(const short8*)(Bs + (wn*32 + 16 + l16)*40 + q*8);
        acc00 = __builtin_amdgcn_mfma_f32_16x16x32_bf16(a0,b0,acc00,0,0,0);
        acc01 = __builtin_amdgcn_mfma_f32_16x16x32_bf16(a0,b1,acc01,0,0,0);
        acc10 = __builtin_amdgcn_mfma_f32_16x16x32_bf16(a1,b0,acc10,0,0,0);
        acc11 = __builtin_amdgcn_mfma_f32_16x16x32_bf16(a1,b1,acc11,0,0,0);
        __syncthreads();
    }
    #pragma unroll
    for (int i=0;i<2;i++){
        int rowb = m0 + wm*32 + i*16 + q*4;
        #pragma unroll
        for (int j=0;j<2;j++){
            int col = n0 + wn*32 + j*16 + l16;
            f32x4 av2 = (i==0) ? ((j==0)?acc00:acc01) : ((j==0)?acc10:acc11);
            #pragma unroll
            for (int r=0;r<4;r++){
                int row = rowb + r;
                u16 o = f2bf(av2[r]);
                if (swz) C[swzE(row,col)] = o;
                else     C[(size_t)row*HID + col] = o;
            }
        }
    }
}
// 64x64-tile GEMM, fp32 out, row guard, optional column-vector add; same prefetch.
// atom=1 -> atomicAdd into pre-zeroed C (split-K use)
__device__ __forceinline__ void gemm64f(int bx, int by, const u16* __restrict__ A, int lda,
                                        const u16* __restrict__ Bt, int ldb,
                                        float* __restrict__ C, int M, int K,
                                        const float* __restrict__ addv, int atom, char* smem)
{
    u16* As = (u16*)smem;
    u16* Bs = (u16*)smem + 64*40;
    const int tid = threadIdx.x;
    const int wave = tid>>6, lane = tid&63;
    const int wm = wave>>1, wn = wave&1;
    const int q = lane>>4, l16 = lane&15;
    const int m0 = bx*64, n0 = by*64;
    const int sm = tid>>2, sk = (tid&3)*8;
    f32x4 acc00={0,0,0,0}, acc01={0,0,0,0}, acc10={0,0,0,0}, acc11={0,0,0,0};
    const bool aOk = (m0+sm) < M;
    const u16* Ap = A + (size_t)(m0+sm)*lda + sk;
    const u16* Bp = Bt + (size_t)(n0+sm)*ldb + sk;
    short8 av = {0,0,0,0,0,0,0,0};
    if (aOk) av = *(const short8*)(Ap);
    short8 bv = *(const short8*)(Bp);
    for (int k0=0; k0<K; k0+=32){
        *(short8*)(As + sm*40 + sk) = av;
        *(short8*)(Bs + sm*40 + sk) = bv;
        __syncthreads();
        if (k0+32 < K){
            if (aOk) av = *(const short8*)(Ap + k0 + 32);
            bv = *(const short8*)(Bp + k0 + 32);
        }
        short8 a0 = *(const short8*)(As + (wm*32      + l16)*40 + q*8);
        short8 a1 = *(const short8*)(As + (wm*32 + 16 + l16)*40 + q*8);
        short8 b0 = *(const short8*)(Bs + (wn*32      + l16)*40 + q*8);
        short8 b1 = *(const short8*)(Bs + (wn*32 + 16 + l16)*40 + q*8);
        acc00 = __builtin_amdgcn_mfma_f32_16x16x32_bf16(a0,b0,acc00,0,0,0);
        acc01 = __builtin_amdgcn_mfma_f32_16x16x32_bf16(a0,b1,acc01,0,0,0);
        acc10 = __builtin_amdgcn_mfma_f32_16x16x32_bf16(a1,b0,acc10,0,0,0);
        acc11 = __builtin_amdgcn_mfma_f32_16x16x32_bf16(a1,b1,acc11,0,0,0);
        __syncthreads();
    }
    #pragma unroll
    for (int i=0;i<2;i++){
        int rowb = m0 + wm*32 + i*16 + q*4;
        #pragma unroll
        for (int j=0;j<2;j++){
            int col = n0 + wn*32 + j*16 + l16;
            f32x4 av2 = (i==0) ? ((j==0)?acc00:acc01) : ((j==0)?acc10:acc11);
            float add = addv ? addv[col] : 0.f;
            #pragma unroll
            for (int r=0;r<4;r++){
                int row = rowb + r;
                if (row < M){
                    float v = av2[r] + add;
                    if (atom) atomicAdd(&C[(size_t)row*HID + col], v);
                    else      C[(size_t)row*HID + col] = v;
                }
            }
        }
    }
}
// bf16 transpose tile (src[R=2560 rows? generic], here fuseW [2560,960] -> fuseWT [960,2560])
__device__ __forceinline__ void transpose_tile(int bx, int by, const u16* __restrict__ src,
                                               u16* __restrict__ dst, int R, int C, char* smem)
{
    u16 (*tl)[33] = (u16(*)[33])smem;
    int c0 = bx*32, r0 = by*32;
    int tx = threadIdx.x & 31, ty = threadIdx.x >> 5;   // 32x8
    #pragma unroll
    for (int i=0;i<4;i++) tl[ty+i*8][tx] = src[(size_t)(r0+ty+i*8)*C + c0+tx];
    __syncthreads();
    #pragma unroll
    for (int i=0;i<4;i++) dst[(size_t)(c0+ty+i*8)*R + r0+tx] = tl[tx][ty+i*8];
}
// split-K vec-mat, += into pre-zeroed out
__device__ __forceinline__ void vecmat_body(int bx, int by, const float* __restrict__ v,
                                            const u16* __restrict__ M, float* __restrict__ out, char* smem)
{
    float (*part)[64] = (float(*)[64])smem;
    int tid = threadIdx.x;
    int cl = tid & 63;
    int c = bx*64 + cl;
    int kg = tid >> 6;
    int k0 = by*60 + kg*15;
    float s = 0.f;
    #pragma unroll
    for (int i=0;i<15;i++) s += v[k0+i]*bf2f(M[(size_t)(k0+i)*HID + c]);
    part[kg][cl] = s;
    __syncthreads();
    if (kg==0) atomicAdd(&out[c], part[0][cl]+part[1][cl]+part[2][cl]+part[3][cl]);
}
// 256-thread scan + dinv
__device__ __forceinline__ void scandinv_body(const int* __restrict__ deg, int* __restrict__ off,
                                              int* __restrict__ cur, float* __restrict__ dinv, char* smem)
{
    int* ps = (int*)smem;
    int t = threadIdx.x;
    const int chunk = N_NODES/256; // 64
    int base0 = t*chunk;
    int s = 0;
    for (int i=0;i<chunk;i++) s += deg[base0+i];
    ps[t] = s; __syncthreads();
    for (int ofs=1; ofs<256; ofs<<=1){
        int v = ps[t];
        int add = (t>=ofs) ? ps[t-ofs] : 0;
        __syncthreads();
        ps[t] = v + add;
        __syncthreads();
    }
    int run = (t==0) ? 0 : ps[t-1];
    for (int i=0;i<chunk;i++){
        int d = deg[base0+i];
        off[base0+i]=run; cur[base0+i]=run; run += d;
        dinv[base0+i] = rsqrtf(1.0f + (float)d);
    }
    if (t==255) off[N_NODES] = run;
}

// ================= fused selector kernels =================
// L1: fuseW transpose (2400 blocks) + hist (256)
__global__ __launch_bounds__(256) void k_L1(const u16* __restrict__ fuseWn, u16* __restrict__ fuseWT,
                                            const int* __restrict__ dst, int* __restrict__ deg){
    __shared__ __attribute__((aligned(16))) char smem[2112];
    int b = blockIdx.x;
    if (b < 2400){
        transpose_tile(b%30, b/30, fuseWn, fuseWT, 2560, HID, smem);
    } else {
        int e = (b-2400)*256 + threadIdx.x;
        if (e < E_EDGES) atomicAdd(&deg[dst[e]], 1);
    }
}
// L2: gemmS pair (Ub, WglobT) (450) + scandinv (1)
__global__ __launch_bounds__(256) void k_L2(const u16* fuseWT, const u16* projWn, const u16* W2n,
                                            u16* Ub, u16* WglobT,
                                            const int* deg, int* off, int* cur, float* dinv){
    __shared__ __attribute__((aligned(16))) char smem[10240];
    int b = blockIdx.x;
    if (b < 450){
        int z = b/225, r = b%225;
        if (z==0) gemm_sq(r%15, r/15, fuseWT+640, 2560, projWn, HID, Ub, 0, smem);
        else      gemm_sq(r%15, r/15, fuseWT+1600, 2560, W2n, HID, WglobT, 0, smem);
    } else {
        scandinv_body(deg, off, cur, dinv, smem);
    }
}
// L3: WbigS = (Ub @ W2^T) swizzled (225) + gemmB fgA/pWbM (75) + scatter (256)
__global__ __launch_bounds__(256) void k_L3(const u16* Ub, const u16* W2n, u16* WbigS,
                                            const u16* fgeN, const u16* posN, const u16* fuseWT,
                                            float* fgA, float* pWbM,
                                            const int* src, const int* dst, const float* dinv,
                                            int* cur, int* csr_s, float* csr_w){
    __shared__ __attribute__((aligned(16))) char smem[10240];
    int b = blockIdx.x;
    if (b < 225){
        gemm_sq(b%15, b/15, Ub, HID, W2n, HID, WbigS, 1, smem);
    } else if (b < 300){
        int bb = b-225;
        if (bb < 60) gemm64f(bb%4, bb/4, fgeN, 512, fuseWT, 2560, fgA, NFG, 512, nullptr, 0, smem);
        else         gemm64f(0, bb-60, posN, 128, fuseWT+512, 2560, pWbM, FMAXF, 128, nullptr, 0, smem);
    } else {
        int e = (b-300)*256 + threadIdx.x;
        if (e < E_EDGES){
            int s = src[e], d = dst[e];
            int p = atomicAdd(&cur[d], 1);
            csr_s[p] = s;
            csr_w[p] = dinv[s]*dinv[d];
        }
    }
}
// L4: fused aggx+h1 (8192 blocks, 2 nodes each) + vecmat3 (720)
__global__ __launch_bounds__(256) void k_L4(const u16* __restrict__ gxn, const float* __restrict__ dinv,
                                            const int* __restrict__ off, const int* __restrict__ csr_s,
                                            const float* __restrict__ csr_w,
                                            const u16* __restrict__ W1, const u16* __restrict__ b1,
                                            u16* __restrict__ h1b,
                                            const float* b2f, const float* projbf, const u16* fuseWn,
                                            const u16* projWn, float* tvb, float* cC, float* gvec){
    __shared__ __attribute__((aligned(16))) char smem[1024];
    int b = blockIdx.x;
    if (b < 8192){
        float* a2 = (float*)smem;     // [2][8]
        int t = threadIdx.x;
        int h = t>>7, tl = t&127;
        int n = b*2 + h;
        if (tl < 5){
            int k = tl;
            float di = dinv[n], sw = di*di;
            float a = sw * bf2f(gxn[n*5+k]);
            int j0 = off[n], j1 = off[n+1];
            int j = j0;
            // batch-4 neighbor processing for MLP (order preserved)
            for (; j+4<=j1; j+=4){
                int   s0=csr_s[j],   s1=csr_s[j+1],   s2=csr_s[j+2],   s3=csr_s[j+3];
                float w0=csr_w[j],   w1=csr_w[j+1],   w2=csr_w[j+2],   w3=csr_w[j+3];
                float g0=bf2f(gxn[s0*5+k]), g1=bf2f(gxn[s1*5+k]);
                float g2=bf2f(gxn[s2*5+k]), g3=bf2f(gxn[s3*5+k]);
                a += w0*g0; a += w1*g1; a += w2*g2; a += w3*g3;
            }
            for (; j<j1; j++) a += csr_w[j]*bf2f(gxn[csr_s[j]*5+k]);
            a2[h*8+k] = a;
        }
        __syncthreads();
        if (tl < 120){
            int c8 = tl*8;
            float a[5];
            #pragma unroll
            for (int k=0;k<5;k++) a[k] = a2[h*8+k];
            float r[8];
            short8 bb = *(const short8*)(b1 + c8);
            #pragma unroll
            for (int j=0;j<8;j++) r[j] = bf2f(((u16*)&bb)[j]);
            #pragma unroll
            for (int k=0;k<5;k++){
                short8 wv = *(const short8*)(W1 + k*HID + c8);
                #pragma unroll
                for (int j=0;j<8;j++) r[j] += a[k]*bf2f(((u16*)&wv)[j]);
            }
            short8 o;
            #pragma unroll
            for (int j=0;j<8;j++) ((u16*)&o)[j] = f2bf(fmaxf(r[j],0.f));
            *(short8*)(h1b + (size_t)n*HID + c8) = o;
        }
    } else {
        int bb = b - 8192;
        int z = bb/240, r = bb%240;
        if (z==0)      vecmat_body(r%15, r/15, b2f,    projWn,            tvb,  smem);
        else if (z==1) vecmat_body(r%15, r/15, projbf, fuseWn + 640*HID,  cC,   smem);
        else           vecmat_body(r%15, r/15, b2f,    fuseWn + 1600*HID, gvec, smem);
    }
}
// L5: p1 (4096) + vecmat vb (240) + addc c0 (4) + zero Gc (240)
// p1 neighbor loop batch-4 pipelined (R6). R8's column-sliced variant REGRESSED
// (+9.7 us): it halved coalescing width (240 B vs 1920 B per row access), re-read
// the csr index stream 8x, and its L2-residency model was defeated by the P1b
// write stream. Keep the full-row form.
__global__ __launch_bounds__(256) void k_L5(const u16* __restrict__ h1b, const float* __restrict__ dinv,
                                            const int* __restrict__ off, const int* __restrict__ csr_s,
                                            const float* __restrict__ csr_w, u16* __restrict__ P1b,
                                            const float* tvb, const u16* fuseWn, float* vb,
                                            const float* cC, const float* gvec, const u16* fusebn, float* c0,
                                            float* __restrict__ Gc){
    __shared__ __attribute__((aligned(16))) char smem[1024];
    int b = blockIdx.x;
    if (b < 4096){
        int wv = threadIdx.x>>6, lane = threadIdx.x&63;
        int n = b*4 + wv;
        int c = lane*16;
        bool act = lane < 60;
        float di = dinv[n], sw = di*di;
        float acc[16];
        if (act){
            short8 h0 = *(const short8*)(h1b + (size_t)n*HID + c);
            short8 h1v = *(const short8*)(h1b + (size_t)n*HID + c + 8);
            #pragma unroll
            for (int j=0;j<8;j++){ acc[j] = sw*bf2f(((u16*)&h0)[j]); acc[8+j] = sw*bf2f(((u16*)&h1v)[j]); }
        } else {
            #pragma unroll
            for (int j=0;j<16;j++) acc[j] = 0.f;
        }
        int j0 = off[n], j1 = off[n+1];
        int j = j0;
        for (; j+4<=j1; j+=4){
            int   s0=csr_s[j],   s1=csr_s[j+1],   s2=csr_s[j+2],   s3=csr_s[j+3];
            float w0=csr_w[j],   w1=csr_w[j+1],   w2=csr_w[j+2],   w3=csr_w[j+3];
            if (act){
                const u16* p0 = h1b + (size_t)s0*HID + c;
                const u16* p1 = h1b + (size_t)s1*HID + c;
                const u16* p2 = h1b + (size_t)s2*HID + c;
                const u16* p3 = h1b + (size_t)s3*HID + c;
                short8 a0 = *(const short8*)(p0), b0 = *(const short8*)(p0+8);
                short8 a1 = *(const short8*)(p1), b1v = *(const short8*)(p1+8);
                short8 a2 = *(const short8*)(p2), b2 = *(const short8*)(p2+8);
                short8 a3 = *(const short8*)(p3), b3 = *(const short8*)(p3+8);
                #pragma unroll
                for (int j2=0;j2<8;j2++){ acc[j2] += w0*bf2f(((u16*)&a0)[j2]); acc[8+j2] += w0*bf2f(((u16*)&b0)[j2]); }
                #pragma unroll
                for (int j2=0;j2<8;j2++){ acc[j2] += w1*bf2f(((u16*)&a1)[j2]); acc[8+j2] += w1*bf2f(((u16*)&b1v)[j2]); }
                #pragma unroll
                for (int j2=0;j2<8;j2++){ acc[j2] += w2*bf2f(((u16*)&a2)[j2]); acc[8+j2] += w2*bf2f(((u16*)&b2)[j2]); }
                #pragma unroll
                for (int j2=0;j2<8;j2++){ acc[j2] += w3*bf2f(((u16*)&a3)[j2]); acc[8+j2] += w3*bf2f(((u16*)&b3)[j2]); }
            }
        }
        for (; j<j1; j++){
            int s = csr_s[j]; float w = csr_w[j];
            if (act){
                short8 v0 = *(const short8*)(h1b + (size_t)s*HID + c);
                short8 v1 = *(const short8*)(h1b + (size_t)s*HID + c + 8);
                #pragma unroll
                for (int j2=0;j2<8;j2++){ acc[j2] += w*bf2f(((u16*)&v0)[j2]); acc[8+j2] += w*bf2f(((u16*)&v1)[j2]); }
            }
        }
        if (act){
            short8 o0, o1;
            #pragma unroll
            for (int j2=0;j2<8;j2++){ ((u16*)&o0)[j2] = f2bf(acc[j2]); ((u16*)&o1)[j2] = f2bf(acc[8+j2]); }
            *(short8*)(P1b + (size_t)n*HID + c) = o0;
            *(short8*)(P1b + (size_t)n*HID + c + 8) = o1;
        }
    } else if (b < 4336){
        int bb = b - 4096;
        vecmat_body(bb%15, bb/15, tvb, fuseWn + 640*HID, vb, smem);
    } else if (b < 4340){
        int c = (b-4336)*256 + threadIdx.x;
        if (c < HID) c0[c] = cC[c] + gvec[c] + bf2f(fusebn[c]);
    } else {
        int id = (b-4340)*256 + threadIdx.x;   // 240*256 = 61440 = (256*960)/4
        *(f32x4*)(Gc + (size_t)id*4) = (f32x4){0.f,0.f,0.f,0.f};
    }
}
// L6: pr (2048, XCD-chunk-swizzled) + gm split-2 (240)
// pr: XCD swizzle (work = (b%8)*256 + b/8, bijective since 2048%8==0) groups the 8
// blocks of each molecule (120 KB P1b window) onto ONE XCD; each XCD's chunk covers
// 32 molecules = 3.84 MB — fits its 4 MB private L2. (R7: −14 µs.)
// Indices preloaded via 4x int4 for MLP (R6).
__global__ __launch_bounds__(256) void k_L6(const u16* __restrict__ P1b, const int* __restrict__ fgi,
                                            const int* __restrict__ ptr, u16* __restrict__ prb,
                                            float* __restrict__ evec, u16* __restrict__ maskb,
                                            float* __restrict__ maskf, const int* __restrict__ flag,
                                            u16* __restrict__ gmb){
    int b = blockIdx.x;
    if (b < 2048){
        int wb = (b&7)*256 + (b>>3);           // XCD-chunked work id
        int wv = threadIdx.x>>6, lane = threadIdx.x&63;
        int bf = wb*4 + wv;
        int mb = bf >> 5;
        int base = ptr[mb];
        int c = lane*16;
        bool act = lane < 60;
        // preload all 16 indices (64 B, wave-uniform broadcast)
        const int4* fp4 = (const int4*)(fgi + bf*AMAXA);
        int4 q0 = fp4[0], q1 = fp4[1], q2 = fp4[2], q3 = fp4[3];
        int idxv[16] = {q0.x,q0.y,q0.z,q0.w, q1.x,q1.y,q1.z,q1.w,
                        q2.x,q2.y,q2.z,q2.w, q3.x,q3.y,q3.z,q3.w};
        int cnt = 0;
        #pragma unroll
        for (int a=0;a<AMAXA;a++) cnt += (idxv[a] >= 0) ? 1 : 0;
        float acc[16];
        #pragma unroll
        for (int j=0;j<16;j++) acc[j] = 0.f;
        #pragma unroll
        for (int a=0;a<AMAXA;a++){
            int idx = idxv[a];
            if (idx >= 0 && act){
                const u16* rp = P1b + (size_t)(base+idx)*HID + c;
                short8 v0 = *(const short8*)(rp);
                short8 v1 = *(const short8*)(rp + 8);
                #pragma unroll
                for (int j=0;j<8;j++){ acc[j] += bf2f(((u16*)&v0)[j]); acc[8+j] += bf2f(((u16*)&v1)[j]); }
            }
        }
        float inv = (cnt>0) ? 1.0f/(float)cnt : 0.0f;
        if (act){
            short8 o0, o1;
            #pragma unroll
            for (int j=0;j<8;j++){ ((u16*)&o0)[j] = f2bf(acc[j]*inv); ((u16*)&o1)[j] = f2bf(acc[8+j]*inv); }
            *(short8*)(prb + swzA(bf, c)) = o0;
            *(short8*)(prb + swzA(bf, c+8)) = o1;
        }
        if (lane == 0){
            float e = (cnt>0) ? 1.0f : 0.0f;
            evec[bf] = e;
            if (*flag) maskf[bf] = e;
            else       maskb[bf] = f2bf(e);
        }
    } else {
        // gm: 240 blocks; 2 threads per (mol, c8) item, 32 nodes each, pair-combine
        int bb = b - 2048;
        int idt = bb*256 + threadIdx.x;        // < 61440
        int item = idt >> 1, half = idt & 1;   // item < 30720 = 256*120
        int mb = item / 120; int c8 = (item - mb*120)*8;
        const u16* Pp = P1b + (size_t)(mb*NPM + half*32)*HID + c8;
        float s[8] = {0,0,0,0,0,0,0,0};
        for (int i=0;i<32;i++){
            short8 v = *(const short8*)(Pp + (size_t)i*HID);
            #pragma unroll
            for (int j=0;j<8;j++) s[j] += bf2f(((u16*)&v)[j]);
        }
        #pragma unroll
        for (int j=0;j<8;j++) s[j] += __shfl_xor(s[j], 1, 64);
        if (half == 0){
            const float inv = 1.0f/(float)NPM;
            short8 o;
            #pragma unroll
            for (int j=0;j<8;j++) ((u16*)&o)[j] = f2bf(s[j]*inv);
            *(short8*)(gmb + (size_t)mb*HID + c8) = o;
        }
    }
}
// L7: Gc += gm @ WglobT^T (+c0 on first half), split-K2 atomic into pre-zeroed Gc (120 blocks)
__global__ __launch_bounds__(256) void k_L7(const u16* gmb, const u16* WglobT, float* Gc, const float* c0){
    __shared__ __attribute__((aligned(16))) char smem[10240];
    int b = blockIdx.x;
    int z = b/60, r = b%60;
    gemm64f(r%4, r/4, gmb + z*480, HID, WglobT + z*480, HID, Gc, B_MOL, 480,
            z ? nullptr : c0, 1, smem);
}

// L8 final GEMM: out[8192,960] = prb @ WbigS^T + epilogue
// BM=128, BN=96, BK=32; 8 waves (512 threads) — each wave computes a 32x48
// sub-tile (2x3 frags). TRIPLE-buffered staging, depth-2 prefetch with COUNTED vmcnt:
// waves 0-6 each stage 2 regions/stage (steady-state vmcnt(2)), wave 7 stages nothing.
// Epilogue: i-outer/j-inner (j-outer caused partial-cacheline RMW, R2). grid 64x10=640
__global__ __launch_bounds__(512) void k_gemmF(
    const u16* __restrict__ A, const u16* __restrict__ Bt,
    float* __restrict__ Cf, u16* __restrict__ Cb,
    const int* __restrict__ fg_type, const float* __restrict__ evec,
    const float* __restrict__ fgA, const float* __restrict__ pWbM,
    const float* __restrict__ vb, const float* __restrict__ Gc,
    const int* __restrict__ flag)
{
    __shared__ __attribute__((aligned(16))) u16 S[3][14*512];   // A regions 0..7, B regions 8..13
    const int tid = threadIdx.x;
    const int wave = tid>>6, lane = tid&63;
    const int wm = wave&3, wn = wave>>2;        // 4 row-groups x 2 col-groups
    const int q = lane>>4, l16 = lane&15;
    const int m0 = blockIdx.x*128, n0 = blockIdx.y*96;
    const int R0 = blockIdx.x*8, N0 = blockIdx.y*6;

    f32x4 acc[2][3];
    #pragma unroll
    for (int i=0;i<2;i++)
        #pragma unroll
        for (int j=0;j<3;j++) acc[i][j] = (f32x4){0,0,0,0};

    // staging: wave w (w<7) owns regions 2w and 2w+1 (regions 0..7 = A rows, 8..13 = B cols)
    const int r0 = wave*2, r1 = wave*2+1;
    const bool stager = (wave < 7);
    const u16* gP0 = (r0 < 8) ? A  + ((size_t)(R0 + r0    )*30)*512 + lane*8
                              : Bt + ((size_t)(N0 + r0 - 8)*30)*512 + lane*8;
    const u16* gP1 = (r1 < 8) ? A  + ((size_t)(R0 + r1    )*30)*512 + lane*8
                              : Bt + ((size_t)(N0 + r1 - 8)*30)*512 + lane*8;

    u16* sA = &S[0][0];
    u16* sB = &S[1][0];
    u16* sC = &S[2][0];

    // prologue: stage 0 and 1; wait stage 0 complete (stage 1 stays in flight)
    if (stager){
        gload_lds16(gP0,        sA + r0*512);
        gload_lds16(gP1,        sA + r1*512);
        gload_lds16(gP0 + 512,  sB + r0*512);
        gload_lds16(gP1 + 512,  sB + r1*512);
        asm volatile("s_waitcnt vmcnt(2)" ::: "memory");
    }
    __builtin_amdgcn_s_barrier();

    for (int kc=0; kc<30; kc++){
        // issue stage kc+2 into sC (buffer last read at iter kc-1; a barrier intervened)
        if (stager && kc+2 < 30){
            const int kn = (kc+2)*512;
            gload_lds16(gP0 + kn, sC + r0*512);
            gload_lds16(gP1 + kn, sC + r1*512);
        }
        // compute from sA (stage kc — complete per last barrier's preceding vmcnt)
        short8 af[2], bfr[3];
        #pragma unroll
        for (int i=0;i<2;i++) af[i] = *(const short8*)(sA + (wm*2+i)*512 + lane*8);
        #pragma unroll
        for (int j=0;j<3;j++) bfr[j] = *(const short8*)(sA + (8+wn*3+j)*512 + lane*8);
        __builtin_amdgcn_s_setprio(1);
        #pragma unroll
        for (int i=0;i<2;i++)
            #pragma unroll
            for (int j=0;j<3;j++)
                acc[i][j] = __builtin_amdgcn_mfma_f32_16x16x32_bf16(af[i], bfr[j], acc[i][j], 0,0,0);
        __builtin_amdgcn_s_setprio(0);
        if (kc < 29){
            if (stager){
                if (kc < 28) asm volatile("s_waitcnt vmcnt(2)" ::: "memory");  // kc+1 done, kc+2 in flight
                else         asm volatile("s_waitcnt vmcnt(0)" ::: "memory");  // drain last stage
            }
            __builtin_amdgcn_s_barrier();
        }
        // rotate buffers
        u16* t = sA; sA = sB; sB = sC; sC = t;
    }

    const int isf = *flag;
    #pragma unroll
    for (int i=0;i<2;i++){
        int rowb = m0 + wm*32 + i*16 + q*4;
        #pragma unroll
        for (int r=0;r<4;r++){
            int row = rowb + r;
            int bb = row>>5, ff = row&31;
            int ty = fg_type[row];
            float e = evec[row];
            #pragma unroll
            for (int j=0;j<3;j++){
                int col = n0 + wn*48 + j*16 + l16;
                float v = acc[i][j][r]
                        + fgA[(size_t)ty*HID+col] + pWbM[ff*HID+col]
                        + e*vb[col] + Gc[(size_t)bb*HID+col];
                if (isf) Cf[(size_t)row*HID + col] = v;
                else     Cb[(size_t)row*HID + col] = f2bf(v);
            }
        }
    }
}

extern "C" void kernel_launch(void* const* d_in, const int* in_sizes, int n_in,
                              void* d_out, int out_size, void* d_ws, size_t ws_size,
                              hipStream_t stream) {
    const int* edge_idx  = (const int*)d_in[1];
    const int* ptr       = (const int*)d_in[3];
    const int* fg_type   = (const int*)d_in[4];
    const int* fg_idx    = (const int*)d_in[5];

    // ---- workspace layout ----
    char* w = (char*)d_ws;
    auto nxt = [&](size_t b)->char*{ char* p = w; w += (b + 255) & ~(size_t)255; return p; };
    u16* big0   = (u16*)nxt((size_t)N_NODES*HID*2);       // fuseWT+Ub -> h1b -> prb(swizzled)
    u16* fuseWT = big0;
    u16* Ub     = big0 + (size_t)HID*2560;
    u16* h1b    = big0;
    u16* prb    = big0;
    u16* P1b    = (u16*)nxt((size_t)N_NODES*HID*2);
    u16*  WbigS  = (u16*) nxt((size_t)HID*HID*2);
    u16*  WglobT = (u16*) nxt((size_t)HID*HID*2);
    float* fgA   = (float*)nxt((size_t)NFG*HID*4);
    float* pWbM  = (float*)nxt((size_t)FMAXF*HID*4);
    float* b2f   = (float*)nxt(HID*4);
    float* projbf= (float*)nxt(HID*4);
    float* tvb   = (float*)nxt(HID*4);   // tvb,cC,gvec,vb contiguous zero-block of 4*HID
    float* cC    = (float*)nxt(HID*4);
    float* gvec  = (float*)nxt(HID*4);
    float* vb    = (float*)nxt(HID*4);
    float* c0    = (float*)nxt(HID*4);
    int*   deg   = (int*)  nxt(N_NODES*4);
    float* dinv  = (float*)nxt(N_NODES*4);
    int*   off   = (int*)  nxt((N_NODES+1)*4);
    int*   cur   = (int*)  nxt(N_NODES*4);
    int*   csr_s = (int*)  nxt(E_EDGES*4);
    float* csr_w = (float*)nxt(E_EDGES*4);
    float* evec  = (float*)nxt(BF_ROWS*4);
    u16*   gmb   = (u16*)  nxt((size_t)B_MOL*HID*2);
    float* Gc    = (float*)nxt((size_t)B_MOL*HID*4);
    int*   flag  = (int*)  nxt(256);
    u16*   region= (u16*)  nxt((size_t)NTOT*2);
    // views into region
    u16* gxn    = region;
    u16* W1n    = region +   81920;
    u16* b1n    = region +   86720;
    u16* W2n    = region +   87680;
    u16* fgeN   = region + 1010240;
    u16* posN   = region + 1115200;
    u16* projWn = region + 1135680;
    u16* fuseWn = region + 2058240;
    u16* fusebn = region + 4515840;

    NormSrcs ns;
    ns.p[0]=d_in[0]; ns.p[1]=d_in[6]; ns.p[2]=d_in[7]; ns.p[3]=d_in[8]; ns.p[4]=d_in[9];
    ns.p[5]=d_in[10]; ns.p[6]=d_in[11]; ns.p[7]=d_in[12]; ns.p[8]=d_in[13]; ns.p[9]=d_in[14]; ns.p[10]=d_in[15];
    // L0: normalize (+flag, +b2f/projbf, zero deg and tvb..vb), 8 elems/thread
    k_normAll<<<(NTOT/8+255)/256,256,0,stream>>>(ns, region, b2f, projbf, tvb, flag, deg);
    // L1: transpose fuseW + hist
    k_L1<<<2656,256,0,stream>>>(fuseWn, fuseWT, edge_idx + E_EDGES, deg);
    // L2: Ub, WglobT + scan/dinv
    k_L2<<<451,256,0,stream>>>(fuseWT, projWn, W2n, Ub, WglobT, deg, off, cur, dinv);
    // L3: WbigS(swz) + fgA/pWbM + scatter
    k_L3<<<556,256,0,stream>>>(Ub, W2n, WbigS, fgeN, posN, fuseWT, fgA, pWbM,
                               edge_idx, edge_idx + E_EDGES, dinv, cur, csr_s, csr_w);
    // L4: aggx+h1 fused + vecmat3 (tvb,cC,gvec)
    k_L4<<<8912,256,0,stream>>>(gxn, dinv, off, csr_s, csr_w, W1n, b1n, h1b,
                                b2f, projbf, fuseWn, projWn, tvb, cC, gvec);
    // L5: p1 + vecmat(vb) + addc(c0) + zero Gc
    k_L5<<<4580,256,0,stream>>>(h1b, dinv, off, csr_s, csr_w, P1b,
                                tvb, fuseWn, vb, cC, gvec, fusebn, c0, Gc);
    // L6: pr (swizzled prb + mask, XCD-chunked) + gm (split-2, 240 blocks)
    k_L6<<<2288,256,0,stream>>>(P1b, fg_idx, ptr, prb, evec,
                                (u16*)d_out + OUT1, (float*)d_out + OUT1, flag, gmb);
    // L7: Gc = gm @ (W2 Wd) + c0, split-K2 atomic (120 blocks)
    k_L7<<<120,256,0,stream>>>(gmb, WglobT, Gc, c0);
    // L8: final GEMM + epilogue (512 threads, 8 waves)
    k_gemmF<<<dim3(64,10),512,0,stream>>>(prb, WbigS, (float*)d_out, (u16*)d_out,
                                          fg_type, evec, fgA, pWbM, vb, Gc, flag);
    (void)in_sizes; (void)n_in; (void)out_size; (void)ws_size;
}